// Round 8
// baseline (851.357 us; speedup 1.0000x reference)
//
#include <hip/hip_runtime.h>
#include <hip/hip_bf16.h>
#include <stdint.h>

// QuantLinear GPTQ 4-bit: out[8192,11008] = x[8192,4096] . W[4096,11008] + bias
#define M_DIM 8192
#define K_DIM 4096
#define N_DIM 11008

typedef __bf16 bf16x8 __attribute__((ext_vector_type(8)));
typedef float f32x4 __attribute__((ext_vector_type(4)));

typedef __attribute__((address_space(1))) const void global_cvoid;
typedef __attribute__((address_space(3))) void lds_void;

__device__ __forceinline__ unsigned short f2bf(float f) {
  unsigned int u = __float_as_uint(f);
  u += 0x7fffu + ((u >> 16) & 1u);
  return (unsigned short)(u >> 16);
}

__device__ __forceinline__ void gload_lds16(const void* g, void* l) {
  // async global->LDS: each lane's 16B lands at lds_base + lane*16 (linear dest)
  __builtin_amdgcn_global_load_lds((global_cvoid*)g, (lds_void*)l, 16, 0, 0);
}

// ---------------- stage 1: x fp32 -> bf16 ----------------
__global__ void k_convert_x(const float* __restrict__ x, unsigned short* __restrict__ xb) {
  const int nthreads = gridDim.x * blockDim.x;
  int tid = blockIdx.x * blockDim.x + threadIdx.x;
  const int n8 = (M_DIM * K_DIM) / 8;
  for (int i = tid; i < n8; i += nthreads) {
    const float4* p = (const float4*)x + (size_t)i * 2;
    float4 a = p[0], b = p[1];
    union { unsigned short h[8]; uint4 u; } r;
    r.h[0] = f2bf(a.x); r.h[1] = f2bf(a.y); r.h[2] = f2bf(a.z); r.h[3] = f2bf(a.w);
    r.h[4] = f2bf(b.x); r.h[5] = f2bf(b.y); r.h[6] = f2bf(b.z); r.h[7] = f2bf(b.w);
    ((uint4*)xb)[i] = r.u;
  }
}

// ---------------- stage 2: dequant W -> bf16 W^T [N][K] ----------------
__global__ void k_dequant_w(const int* __restrict__ qw, const int* __restrict__ qz,
                            const float* __restrict__ sc, unsigned short* __restrict__ wt) {
  int n = blockIdx.x * blockDim.x + threadIdx.x;
  int k8_0 = blockIdx.y * 8;
  int g = (k8_0 * 8) >> 7;
  float s = sc[g * N_DIM + n];
  int zq = (qz[g * (N_DIM / 8) + (n >> 3)] >> ((n & 7) * 4)) & 15;
  float zs = s * (float)zq;
  #pragma unroll
  for (int i = 0; i < 8; ++i) {
    int k8 = k8_0 + i;
    int w = qw[(size_t)k8 * N_DIM + n];
    union { unsigned short h[8]; uint4 u; } r;
    #pragma unroll
    for (int j = 0; j < 8; ++j) {
      float v = s * (float)((w >> (4 * j)) & 15) - zs;
      r.h[j] = f2bf(v);
    }
    *(uint4*)(wt + (size_t)n * K_DIM + (size_t)k8 * 8) = r.u;
  }
}

// ---------------- stage 3: 256x256 GEMM, 16 waves (4 waves/SIMD) ----------------
// A = Xb [M][K], B = Wt [N][K]. 16 waves in 4x4 grid, per-wave 64x64 out,
// acc = 64 VGPR -> fits the 128-VGPR/wave cap that 4 waves/SIMD requires.
// Per K-tile: 2 phases (kk-slice); phase = 8 ds_reads + 16 MFMA.
// 2 barriers + 2 per-wave vmcnt(0) per 2 K-tiles; stage-issues lead their
// drain by >=1 full phase. Race audit: a buffer is staged at phase-top only
// after its readers drained at the preceding vmcnt(0)+barrier (per-wave vmcnt
// vouches own stages, barrier makes it collective).
// Swizzle: 16B slot ^= (row&7) on stage-source and reads (involution).

#define MFMAP() do { \
  __builtin_amdgcn_s_setprio(1); \
  acc[0][0] = __builtin_amdgcn_mfma_f32_16x16x32_bf16(afr[0], bfr[0], acc[0][0], 0, 0, 0); \
  acc[0][1] = __builtin_amdgcn_mfma_f32_16x16x32_bf16(afr[0], bfr[1], acc[0][1], 0, 0, 0); \
  acc[0][2] = __builtin_amdgcn_mfma_f32_16x16x32_bf16(afr[0], bfr[2], acc[0][2], 0, 0, 0); \
  acc[0][3] = __builtin_amdgcn_mfma_f32_16x16x32_bf16(afr[0], bfr[3], acc[0][3], 0, 0, 0); \
  acc[1][0] = __builtin_amdgcn_mfma_f32_16x16x32_bf16(afr[1], bfr[0], acc[1][0], 0, 0, 0); \
  acc[1][1] = __builtin_amdgcn_mfma_f32_16x16x32_bf16(afr[1], bfr[1], acc[1][1], 0, 0, 0); \
  acc[1][2] = __builtin_amdgcn_mfma_f32_16x16x32_bf16(afr[1], bfr[2], acc[1][2], 0, 0, 0); \
  acc[1][3] = __builtin_amdgcn_mfma_f32_16x16x32_bf16(afr[1], bfr[3], acc[1][3], 0, 0, 0); \
  acc[2][0] = __builtin_amdgcn_mfma_f32_16x16x32_bf16(afr[2], bfr[0], acc[2][0], 0, 0, 0); \
  acc[2][1] = __builtin_amdgcn_mfma_f32_16x16x32_bf16(afr[2], bfr[1], acc[2][1], 0, 0, 0); \
  acc[2][2] = __builtin_amdgcn_mfma_f32_16x16x32_bf16(afr[2], bfr[2], acc[2][2], 0, 0, 0); \
  acc[2][3] = __builtin_amdgcn_mfma_f32_16x16x32_bf16(afr[2], bfr[3], acc[2][3], 0, 0, 0); \
  acc[3][0] = __builtin_amdgcn_mfma_f32_16x16x32_bf16(afr[3], bfr[0], acc[3][0], 0, 0, 0); \
  acc[3][1] = __builtin_amdgcn_mfma_f32_16x16x32_bf16(afr[3], bfr[1], acc[3][1], 0, 0, 0); \
  acc[3][2] = __builtin_amdgcn_mfma_f32_16x16x32_bf16(afr[3], bfr[2], acc[3][2], 0, 0, 0); \
  acc[3][3] = __builtin_amdgcn_mfma_f32_16x16x32_bf16(afr[3], bfr[3], acc[3][3], 0, 0, 0); \
  __builtin_amdgcn_s_setprio(0); \
} while (0)

// load A(4) + B(4) fragments for kk-slice of buffer buf
#define LOADF(buf, kk) do { \
  const unsigned short* ah_ = sh + ((buf)*4 + ha) * 8192; \
  const unsigned short* bh_ = sh + ((buf)*4 + 2 + hb) * 8192; \
  afr[0] = *(const bf16x8*)(const void*)(ah_ + (aB0 ^ ((kk) << 5))); \
  afr[1] = *(const bf16x8*)(const void*)(ah_ + (aB1 ^ ((kk) << 5))); \
  afr[2] = *(const bf16x8*)(const void*)(ah_ + (aB2 ^ ((kk) << 5))); \
  afr[3] = *(const bf16x8*)(const void*)(ah_ + (aB3 ^ ((kk) << 5))); \
  bfr[0] = *(const bf16x8*)(const void*)(bh_ + (bB0 ^ ((kk) << 5))); \
  bfr[1] = *(const bf16x8*)(const void*)(bh_ + (bB1 ^ ((kk) << 5))); \
  bfr[2] = *(const bf16x8*)(const void*)(bh_ + (bB2 ^ ((kk) << 5))); \
  bfr[3] = *(const bf16x8*)(const void*)(bh_ + (bB3 ^ ((kk) << 5))); \
} while (0)

// stage one 128x64 half-tile; 16 waves x 1 gload (wave w covers rows w*8..w*8+7)
#define STAGE1(buf, ab, half, kt) do { \
  const unsigned short* g_ = ((ab) ? pB : pA) + ((size_t)(half) * 128) * K_DIM + (kt) * 64; \
  unsigned short* l_ = sh + (((buf)*4 + (ab)*2 + (half)) * 8192) + w * 512; \
  gload_lds16(g_, l_); \
} while (0)

#define STAGE4(buf, kt) do { \
  STAGE1(buf, 0, 0, kt); STAGE1(buf, 0, 1, kt); \
  STAGE1(buf, 1, 0, kt); STAGE1(buf, 1, 1, kt); \
} while (0)

#define WAIT_VM0 asm volatile("s_waitcnt vmcnt(0)" ::: "memory")
#define BAR() do { __builtin_amdgcn_s_barrier(); asm volatile("" ::: "memory"); } while (0)

__global__ __launch_bounds__(1024) void k_gemm(const unsigned short* __restrict__ Xb,
                                               const unsigned short* __restrict__ Wt,
                                               const float* __restrict__ bias,
                                               float* __restrict__ out) {
  __shared__ __align__(16) unsigned short sh[2 * 2 * 2 * 8192];  // 128 KiB

  const int nwg = gridDim.x;                 // 1376, % 8 == 0 -> bijective
  int bid = blockIdx.x;
  int swz = (bid & 7) * (nwg >> 3) + (bid >> 3);
  const int ntn = N_DIM / 256;               // 43
  int mt = swz / ntn;
  int nt = swz % ntn;

  const int tid = threadIdx.x;
  const int w = tid >> 6;        // wave 0..15
  const int lane = tid & 63;
  const int wr = w >> 2;         // 0..3: M sub-tile (64 rows)
  const int wc = w & 3;          // 0..3: N sub-tile (64 cols)
  const int ha = wr >> 1;        // A half (0/1)
  const int hb = wc >> 1;        // B half (0/1)
  const int fr = lane & 15;
  const int fq = lane >> 4;
  const int r7 = fr & 7;

  // staging: per-lane pre-swizzled global source (involution slot^row)
  const int srow = lane >> 3;                 // 0..7
  const int sslot = (lane & 7) ^ srow;        // 16B slot in the 128B row
  const size_t goff = (size_t)(w * 8 + srow) * K_DIM + (size_t)sslot * 8;
  const unsigned short* pA = Xb + (size_t)(mt * 256) * K_DIM + goff;
  const unsigned short* pB = Wt + (size_t)(nt * 256) * K_DIM + goff;

  // fragment element offsets within a [128][64] half; kk=1 addr = base ^ 32
  const int sw8 = (fq ^ r7) << 3;
  const int arb = (wr & 1) * 64;
  const int brb = (wc & 1) * 64;
  const int aB0 = (arb + 0 * 16 + fr) * 64 + sw8;
  const int aB1 = (arb + 1 * 16 + fr) * 64 + sw8;
  const int aB2 = (arb + 2 * 16 + fr) * 64 + sw8;
  const int aB3 = (arb + 3 * 16 + fr) * 64 + sw8;
  const int bB0 = (brb + 0 * 16 + fr) * 64 + sw8;
  const int bB1 = (brb + 1 * 16 + fr) * 64 + sw8;
  const int bB2 = (brb + 2 * 16 + fr) * 64 + sw8;
  const int bB3 = (brb + 3 * 16 + fr) * 64 + sw8;

  f32x4 acc[4][4] = {};
  bf16x8 afr[4];
  bf16x8 bfr[4];

  // prologue: stage tile0 -> buf0
  STAGE4(0, 0);
  WAIT_VM0;
  BAR();

  // main loop: iteration computes tiles 2i (buf0) and 2i+1 (buf1)
  for (int i = 0; i < 31; ++i) {
    int t = 2 * i;
    STAGE4(1, t + 1);            // P1: stage next tile into buf1
    LOADF(0, 0); MFMAP();        //     compute buf0 kk=0
    LOADF(0, 1); MFMAP();        // P2: compute buf0 kk=1
    WAIT_VM0;                    // buf1 landed (issued a full phase ago)
    BAR();
    STAGE4(0, t + 2);            // P3: stage tile t+2 into buf0
    LOADF(1, 0); MFMAP();        //     compute buf1 kk=0
    LOADF(1, 1); MFMAP();        // P4: compute buf1 kk=1
    WAIT_VM0;
    BAR();
  }
  // tail: tiles 62 (buf0), 63 (buf1)
  STAGE4(1, 63);
  LOADF(0, 0); MFMAP();
  LOADF(0, 1); MFMAP();
  WAIT_VM0;
  BAR();
  LOADF(1, 0); MFMAP();
  LOADF(1, 1); MFMAP();

  // epilogue: C/D layout col=lane&15, row=(lane>>4)*4+reg
  const int r0 = mt * 256 + wr * 64 + fq * 4;
  const int c0 = nt * 256 + wc * 64 + fr;
  #pragma unroll
  for (int nj = 0; nj < 4; ++nj) {
    int col = c0 + nj * 16;
    float bv = bias[col];
    #pragma unroll
    for (int mi = 0; mi < 4; ++mi) {
      size_t base = (size_t)(r0 + mi * 16) * N_DIM + col;
      #pragma unroll
      for (int r = 0; r < 4; ++r)
        out[base + (size_t)r * N_DIM] = acc[mi][nj][r] + bv;
    }
  }
}

// ---------------- fallback (ws too small): naive fp32 ----------------
__global__ void k_fallback(const float* __restrict__ x, const int* __restrict__ qw,
                           const int* __restrict__ qz, const float* __restrict__ sc,
                           const float* __restrict__ bias, float* __restrict__ out) {
  int n = blockIdx.x * blockDim.x + threadIdx.x;
  int m = blockIdx.y;
  const float* xr = x + (size_t)m * K_DIM;
  float acc = 0.f;
  for (int g = 0; g < 32; ++g) {
    float s = sc[g * N_DIM + n];
    int zq = (qz[g * (N_DIM / 8) + (n >> 3)] >> ((n & 7) * 4)) & 15;
    float zs = s * (float)zq;
    for (int k8 = g * 16; k8 < g * 16 + 16; ++k8) {
      int w = qw[(size_t)k8 * N_DIM + n];
      #pragma unroll
      for (int j = 0; j < 8; ++j) {
        float wf = s * (float)((w >> (4 * j)) & 15) - zs;
        acc += wf * xr[k8 * 8 + j];
      }
    }
  }
  out[(size_t)m * N_DIM + n] = acc + bias[n];
}

extern "C" void kernel_launch(void* const* d_in, const int* in_sizes, int n_in,
                              void* d_out, int out_size, void* d_ws, size_t ws_size,
                              hipStream_t stream) {
  const float* x  = (const float*)d_in[0];
  const int* qw   = (const int*)d_in[1];
  const int* qz   = (const int*)d_in[2];
  const float* sc = (const float*)d_in[3];
  const float* bias = (const float*)d_in[4];
  float* out = (float*)d_out;

  const size_t xb_bytes = (size_t)M_DIM * K_DIM * 2;
  const size_t wt_bytes = (size_t)N_DIM * K_DIM * 2;
  const size_t need = xb_bytes + wt_bytes;

  if (ws_size >= need) {
    unsigned short* xb = (unsigned short*)d_ws;
    unsigned short* wt = (unsigned short*)((char*)d_ws + xb_bytes);
    k_convert_x<<<dim3(4096), dim3(256), 0, stream>>>(x, xb);
    k_dequant_w<<<dim3(N_DIM / 256, 64), dim3(256), 0, stream>>>(qw, qz, sc, wt);
    k_gemm<<<dim3((M_DIM / 256) * (N_DIM / 256)), dim3(1024), 0, stream>>>(xb, wt, bias, out);
  } else {
    k_fallback<<<dim3(N_DIM / 256, M_DIM), dim3(256), 0, stream>>>(x, qw, qz, sc, bias, out);
  }
}

// Round 9
// 708.530 us; speedup vs baseline: 1.2016x; 1.2016x over previous
//
#include <hip/hip_runtime.h>
#include <hip/hip_bf16.h>
#include <stdint.h>

// QuantLinear GPTQ 4-bit: out[8192,11008] = x[8192,4096] . W[4096,11008] + bias
#define M_DIM 8192
#define K_DIM 4096
#define N_DIM 11008

typedef __bf16 bf16x8 __attribute__((ext_vector_type(8)));
typedef float f32x4 __attribute__((ext_vector_type(4)));

typedef __attribute__((address_space(1))) const void global_cvoid;
typedef __attribute__((address_space(3))) void lds_void;

__device__ __forceinline__ unsigned short f2bf(float f) {
  unsigned int u = __float_as_uint(f);
  u += 0x7fffu + ((u >> 16) & 1u);
  return (unsigned short)(u >> 16);
}

__device__ __forceinline__ void gload_lds16(const void* g, void* l) {
  // async global->LDS: each lane's 16B lands at lds_base + lane*16 (linear dest)
  __builtin_amdgcn_global_load_lds((global_cvoid*)g, (lds_void*)l, 16, 0, 0);
}

// ---------------- stage 1: x fp32 -> bf16 ----------------
__global__ void k_convert_x(const float* __restrict__ x, unsigned short* __restrict__ xb) {
  const int nthreads = gridDim.x * blockDim.x;
  int tid = blockIdx.x * blockDim.x + threadIdx.x;
  const int n8 = (M_DIM * K_DIM) / 8;
  for (int i = tid; i < n8; i += nthreads) {
    const float4* p = (const float4*)x + (size_t)i * 2;
    float4 a = p[0], b = p[1];
    union { unsigned short h[8]; uint4 u; } r;
    r.h[0] = f2bf(a.x); r.h[1] = f2bf(a.y); r.h[2] = f2bf(a.z); r.h[3] = f2bf(a.w);
    r.h[4] = f2bf(b.x); r.h[5] = f2bf(b.y); r.h[6] = f2bf(b.z); r.h[7] = f2bf(b.w);
    ((uint4*)xb)[i] = r.u;
  }
}

// ---------------- stage 2: dequant W -> bf16 W^T [N][K] ----------------
__global__ void k_dequant_w(const int* __restrict__ qw, const int* __restrict__ qz,
                            const float* __restrict__ sc, unsigned short* __restrict__ wt) {
  int n = blockIdx.x * blockDim.x + threadIdx.x;
  int k8_0 = blockIdx.y * 8;
  int g = (k8_0 * 8) >> 7;
  float s = sc[g * N_DIM + n];
  int zq = (qz[g * (N_DIM / 8) + (n >> 3)] >> ((n & 7) * 4)) & 15;
  float zs = s * (float)zq;
  #pragma unroll
  for (int i = 0; i < 8; ++i) {
    int k8 = k8_0 + i;
    int w = qw[(size_t)k8 * N_DIM + n];
    union { unsigned short h[8]; uint4 u; } r;
    #pragma unroll
    for (int j = 0; j < 8; ++j) {
      float v = s * (float)((w >> (4 * j)) & 15) - zs;
      r.h[j] = f2bf(v);
    }
    *(uint4*)(wt + (size_t)n * K_DIM + (size_t)k8 * 8) = r.u;
  }
}

// ---------------- stage 3: 256x256 bf16 GEMM, lead-1 frag pipeline ----------------
// A = Xb [M][K], B = Wt [N][K]. 8 waves (2Mx4N), BK=64, dbuf swizzled LDS.
// Software pipeline: A-fragment registers double-buffered (afrA/afrB by q
// parity); phase q's reads issue in phase q-1, so MFMAQ(q) consumes reads
// ~1 phase (~620 cyc) old -> lgkm wait ~0, LDS pipe services next reads
// UNDER the current MFMA burst. B-frags (all 4 nj x 2 kk) read once at the
// tile's first phase (the once-per-4-phases bubble).
// Stage slots / vmcnt(4) ledger / barrier set {P2,P4,P6,P8} identical to the
// audited round-7 schedule. Lead-1 keeps every region's last read drained
// >=1 barrier before its re-stage (slot-by-slot audit in round-8 notes).
// Swizzle: 16B slot ^= (row&7) on stage-source and reads (involution).

#define MFMA1S(S, mi, nj, kk) \
  acc[mi][nj] = __builtin_amdgcn_mfma_f32_16x16x32_bf16(S[(mi) & 1][kk], bfr[nj][kk], acc[mi][nj], 0, 0, 0)

#define MFMAQ_S(q, S) do { \
  __builtin_amdgcn_s_setprio(1); \
  MFMA1S(S, (q)*2+0, 0, 0); MFMA1S(S, (q)*2+0, 1, 0); MFMA1S(S, (q)*2+0, 2, 0); MFMA1S(S, (q)*2+0, 3, 0); \
  MFMA1S(S, (q)*2+1, 0, 0); MFMA1S(S, (q)*2+1, 1, 0); MFMA1S(S, (q)*2+1, 2, 0); MFMA1S(S, (q)*2+1, 3, 0); \
  MFMA1S(S, (q)*2+0, 0, 1); MFMA1S(S, (q)*2+0, 1, 1); MFMA1S(S, (q)*2+0, 2, 1); MFMA1S(S, (q)*2+0, 3, 1); \
  MFMA1S(S, (q)*2+1, 0, 1); MFMA1S(S, (q)*2+1, 1, 1); MFMA1S(S, (q)*2+1, 2, 1); MFMA1S(S, (q)*2+1, 3, 1); \
  __builtin_amdgcn_s_setprio(0); \
} while (0)

// A fragments (4 x b128) for q-subtile of buffer buf into register set S
#define LOADA_S(S, buf, q) do { \
  const unsigned short* aa_ = sh + (((buf)*2)*2 + wm) * 8192 + (q) * 2048; \
  S[0][0] = *(const bf16x8*)(const void*)(aa_ + aoff0); \
  S[0][1] = *(const bf16x8*)(const void*)(aa_ + aoff1); \
  S[1][0] = *(const bf16x8*)(const void*)(aa_ + 1024 + aoff0); \
  S[1][1] = *(const bf16x8*)(const void*)(aa_ + 1024 + aoff1); \
} while (0)

#define LOADB(buf) do { \
  const unsigned short* bb_ = sh + (((buf)*2 + 1)*2 + (wn >> 1)) * 8192; \
  bfr[0][0] = *(const bf16x8*)(const void*)(bb_ + boff0); \
  bfr[0][1] = *(const bf16x8*)(const void*)(bb_ + boff1); \
  bfr[1][0] = *(const bf16x8*)(const void*)(bb_ + 1024 + boff0); \
  bfr[1][1] = *(const bf16x8*)(const void*)(bb_ + 1024 + boff1); \
  bfr[2][0] = *(const bf16x8*)(const void*)(bb_ + 2048 + boff0); \
  bfr[2][1] = *(const bf16x8*)(const void*)(bb_ + 2048 + boff1); \
  bfr[3][0] = *(const bf16x8*)(const void*)(bb_ + 3072 + boff0); \
  bfr[3][1] = *(const bf16x8*)(const void*)(bb_ + 3072 + boff1); \
} while (0)

#define STAGE(buf, ab, half, kt) do { \
  const unsigned short* g_ = ((ab) ? pB : pA) + ((size_t)(half) * 128) * K_DIM + (kt) * 64; \
  unsigned short* l_ = sh + ((((buf)*2 + (ab))*2 + (half)) * 8192) + w * 1024; \
  gload_lds16(g_, l_); \
  gload_lds16(g_ + 8 * K_DIM, l_ + 512); \
} while (0)

#define WAIT_VM4 asm volatile("s_waitcnt vmcnt(4)" ::: "memory")
#define WAIT_VM0 asm volatile("s_waitcnt vmcnt(0)" ::: "memory")
#define BAR() do { __builtin_amdgcn_s_barrier(); asm volatile("" ::: "memory"); } while (0)

__global__ __launch_bounds__(512, 2) void k_gemm(const unsigned short* __restrict__ Xb,
                                                 const unsigned short* __restrict__ Wt,
                                                 const float* __restrict__ bias,
                                                 float* __restrict__ out) {
  __shared__ __align__(16) unsigned short sh[2 * 2 * 2 * 8192];  // 128 KiB

  const int nwg = gridDim.x;                 // 1376, % 8 == 0 -> bijective
  int bid = blockIdx.x;
  int swz = (bid & 7) * (nwg >> 3) + (bid >> 3);
  const int ntn = N_DIM / 256;               // 43
  int mt = swz / ntn;
  int nt = swz % ntn;

  const int tid = threadIdx.x;
  const int w = tid >> 6;        // wave 0..7
  const int lane = tid & 63;
  const int wm = w >> 2;         // 0..1 (M sub-tile 128)
  const int wn = w & 3;          // 0..3 (N sub-tile 64)
  const int fr = lane & 15;
  const int fq = lane >> 4;

  // staging: per-lane pre-swizzled global source (involution slot^row)
  const int srow = lane >> 3;                 // 0..7
  const int sslot = (lane & 7) ^ srow;        // 16B slot in the 128B row
  const size_t goff = (size_t)srow * K_DIM + (size_t)sslot * 8;
  const unsigned short* pA = Xb + (size_t)(mt * 256 + w * 16) * K_DIM + goff;
  const unsigned short* pB = Wt + (size_t)(nt * 256 + w * 16) * K_DIM + goff;

  // ds_read element offsets (swizzled slot = (kk*4+fq) ^ (row&7), row&7 == fr&7)
  const int aoff0 = fr * 64 + ((fq) ^ (fr & 7)) * 8;
  const int aoff1 = fr * 64 + ((4 + fq) ^ (fr & 7)) * 8;
  const int boff0 = ((wn & 1) * 64 + fr) * 64 + ((fq) ^ (fr & 7)) * 8;
  const int boff1 = ((wn & 1) * 64 + fr) * 64 + ((4 + fq) ^ (fr & 7)) * 8;

  f32x4 acc[8][4] = {};
  bf16x8 afrA[2][2];   // even-q fragment set
  bf16x8 afrB[2][2];   // odd-q fragment set
  bf16x8 bfr[4][2];

  // prologue: tile0 fully (buf0, 8 loads), tile1 B-halves (buf1, 4 loads)
  STAGE(0, 0, 0, 0); STAGE(0, 0, 1, 0); STAGE(0, 1, 0, 0); STAGE(0, 1, 1, 0);
  STAGE(1, 1, 0, 1); STAGE(1, 1, 1, 1);
  WAIT_VM4;                       // tile0's 8 loads done; B(1) x4 in flight
  BAR();

  // main loop: iteration computes tiles 2i (buf0, P1-4) and 2i+1 (buf1, P5-8)
  for (int i = 0; i < 31; ++i) {
    int t = 2 * i;
    // P1
    STAGE(1, 0, 0, t + 1);
    LOADB(0);
    LOADA_S(afrA, 0, 0);
    LOADA_S(afrB, 0, 1);
    MFMAQ_S(0, afrA);
    // P2
    STAGE(1, 0, 1, t + 1);
    LOADA_S(afrA, 0, 2);
    MFMAQ_S(1, afrB);
    BAR();
    // P3
    STAGE(0, 1, 0, t + 2);
    LOADA_S(afrB, 0, 3);
    MFMAQ_S(2, afrA);
    // P4
    STAGE(0, 1, 1, t + 2);
    MFMAQ_S(3, afrB);
    WAIT_VM4;
    BAR();
    // P5
    STAGE(0, 0, 0, t + 2);
    LOADB(1);
    LOADA_S(afrA, 1, 0);
    LOADA_S(afrB, 1, 1);
    MFMAQ_S(0, afrA);
    // P6
    STAGE(0, 0, 1, t + 2);
    LOADA_S(afrA, 1, 2);
    MFMAQ_S(1, afrB);
    BAR();
    // P7
    STAGE(1, 1, 0, t + 3);
    LOADA_S(afrB, 1, 3);
    MFMAQ_S(2, afrA);
    // P8
    STAGE(1, 1, 1, t + 3);
    MFMAQ_S(3, afrB);
    WAIT_VM4;
    BAR();
  }
  // tail: tiles 62 (buf0), 63 (buf1)
  STAGE(1, 0, 0, 63);
  LOADB(0);
  LOADA_S(afrA, 0, 0);
  LOADA_S(afrB, 0, 1);
  MFMAQ_S(0, afrA);
  STAGE(1, 0, 1, 63);
  LOADA_S(afrA, 0, 2);
  MFMAQ_S(1, afrB);
  BAR();
  LOADA_S(afrB, 0, 3);
  MFMAQ_S(2, afrA);
  MFMAQ_S(3, afrB);
  WAIT_VM0;                      // tile63-A (staged this window) fully landed
  BAR();
  LOADB(1);
  LOADA_S(afrA, 1, 0);
  LOADA_S(afrB, 1, 1);
  MFMAQ_S(0, afrA);
  LOADA_S(afrA, 1, 2);
  MFMAQ_S(1, afrB);
  LOADA_S(afrB, 1, 3);
  MFMAQ_S(2, afrA);
  MFMAQ_S(3, afrB);

  // epilogue: C/D layout col=lane&15, row=(lane>>4)*4+reg
  const int r0 = mt * 256 + wm * 128 + fq * 4;
  const int c0 = nt * 256 + wn * 64 + fr;
  #pragma unroll
  for (int nj = 0; nj < 4; ++nj) {
    int col = c0 + nj * 16;
    float bv = bias[col];
    #pragma unroll
    for (int mi = 0; mi < 8; ++mi) {
      size_t base = (size_t)(r0 + mi * 16) * N_DIM + col;
      #pragma unroll
      for (int r = 0; r < 4; ++r)
        out[base + (size_t)r * N_DIM] = acc[mi][nj][r] + bv;
    }
  }
}

// ---------------- fallback (ws too small): naive fp32 ----------------
__global__ void k_fallback(const float* __restrict__ x, const int* __restrict__ qw,
                           const int* __restrict__ qz, const float* __restrict__ sc,
                           const float* __restrict__ bias, float* __restrict__ out) {
  int n = blockIdx.x * blockDim.x + threadIdx.x;
  int m = blockIdx.y;
  const float* xr = x + (size_t)m * K_DIM;
  float acc = 0.f;
  for (int g = 0; g < 32; ++g) {
    float s = sc[g * N_DIM + n];
    int zq = (qz[g * (N_DIM / 8) + (n >> 3)] >> ((n & 7) * 4)) & 15;
    float zs = s * (float)zq;
    for (int k8 = g * 16; k8 < g * 16 + 16; ++k8) {
      int w = qw[(size_t)k8 * N_DIM + n];
      #pragma unroll
      for (int j = 0; j < 8; ++j) {
        float wf = s * (float)((w >> (4 * j)) & 15) - zs;
        acc += wf * xr[k8 * 8 + j];
      }
    }
  }
  out[(size_t)m * N_DIM + n] = acc + bias[n];
}

extern "C" void kernel_launch(void* const* d_in, const int* in_sizes, int n_in,
                              void* d_out, int out_size, void* d_ws, size_t ws_size,
                              hipStream_t stream) {
  const float* x  = (const float*)d_in[0];
  const int* qw   = (const int*)d_in[1];
  const int* qz   = (const int*)d_in[2];
  const float* sc = (const float*)d_in[3];
  const float* bias = (const float*)d_in[4];
  float* out = (float*)d_out;

  const size_t xb_bytes = (size_t)M_DIM * K_DIM * 2;
  const size_t wt_bytes = (size_t)N_DIM * K_DIM * 2;
  const size_t need = xb_bytes + wt_bytes;

  if (ws_size >= need) {
    unsigned short* xb = (unsigned short*)d_ws;
    unsigned short* wt = (unsigned short*)((char*)d_ws + xb_bytes);
    k_convert_x<<<dim3(4096), dim3(256), 0, stream>>>(x, xb);
    k_dequant_w<<<dim3(N_DIM / 256, 64), dim3(256), 0, stream>>>(qw, qz, sc, wt);
    k_gemm<<<dim3((M_DIM / 256) * (N_DIM / 256)), dim3(512), 0, stream>>>(xb, wt, bias, out);
  } else {
    k_fallback<<<dim3(N_DIM / 256, M_DIM), dim3(256), 0, stream>>>(x, qw, qz, sc, bias, out);
  }
}

// Round 10
// 607.437 us; speedup vs baseline: 1.4016x; 1.1664x over previous
//
#include <hip/hip_runtime.h>
#include <hip/hip_bf16.h>
#include <stdint.h>

// QuantLinear GPTQ 4-bit: out[8192,11008] = x[8192,4096] . W[4096,11008] + bias
// i8 path: W' = (q - z) exact in i8; x quantized per-row to i8; per-group
// (128) scales applied on i32 partial accumulators; row scale at epilogue.
#define M_DIM 8192
#define K_DIM 4096
#define N_DIM 11008

typedef int i32x4 __attribute__((ext_vector_type(4)));
typedef float f32x4 __attribute__((ext_vector_type(4)));

typedef __attribute__((address_space(1))) const void global_cvoid;
typedef __attribute__((address_space(3))) void lds_void;

__device__ __forceinline__ void gload_lds16(const void* g, void* l) {
  // async global->LDS: each lane's 16B lands at lds_base + lane*16 (linear dest)
  __builtin_amdgcn_global_load_lds((global_cvoid*)g, (lds_void*)l, 16, 0, 0);
}

// ---------------- stage 1: per-row quantize x -> i8 + row scale ----------------
__global__ void k_quant_x(const float* __restrict__ x, signed char* __restrict__ xq,
                          float* __restrict__ sx) {
  int m = blockIdx.x;                       // 8192 rows
  int tx = threadIdx.x;                     // 256 threads, 16 floats each
  const float4* row = (const float4*)(x + (size_t)m * K_DIM);
  float4 v[4];
  float mx = 0.f;
  #pragma unroll
  for (int i = 0; i < 4; ++i) {
    v[i] = row[tx * 4 + i];
    mx = fmaxf(mx, fmaxf(fmaxf(fabsf(v[i].x), fabsf(v[i].y)),
                         fmaxf(fabsf(v[i].z), fabsf(v[i].w))));
  }
  // wave reduce (64 lanes)
  #pragma unroll
  for (int off = 1; off < 64; off <<= 1)
    mx = fmaxf(mx, __shfl_xor(mx, off));
  __shared__ float wmx[4];
  if ((tx & 63) == 0) wmx[tx >> 6] = mx;
  __syncthreads();
  mx = fmaxf(fmaxf(wmx[0], wmx[1]), fmaxf(wmx[2], wmx[3]));
  mx = fmaxf(mx, 1e-20f);
  float scale = 127.0f / mx;
  if (tx == 0) sx[m] = mx / 127.0f;
  union { signed char c[16]; uint4 u; } p;
  #pragma unroll
  for (int i = 0; i < 4; ++i) {
    p.c[i * 4 + 0] = (signed char)(int)rintf(v[i].x * scale);
    p.c[i * 4 + 1] = (signed char)(int)rintf(v[i].y * scale);
    p.c[i * 4 + 2] = (signed char)(int)rintf(v[i].z * scale);
    p.c[i * 4 + 3] = (signed char)(int)rintf(v[i].w * scale);
  }
  ((uint4*)(xq + (size_t)m * K_DIM))[tx] = p.u;
}

// ---------------- stage 2: unpack W -> i8 W'^T [N][K], W' = q - z ----------------
__global__ void k_dequant_w8(const int* __restrict__ qw, const int* __restrict__ qz,
                             signed char* __restrict__ wt) {
  int n = blockIdx.x * blockDim.x + threadIdx.x;   // [0, 11008)
  int k8_0 = blockIdx.y * 8;                       // grid.y = 64
  int g = (k8_0 * 8) >> 7;                         // group, uniform per block
  int zq = (qz[g * (N_DIM / 8) + (n >> 3)] >> ((n & 7) * 4)) & 15;
  #pragma unroll
  for (int i = 0; i < 8; ++i) {
    int k8 = k8_0 + i;
    int w = qw[(size_t)k8 * N_DIM + n];
    union { signed char c[8]; uint2 u; } r;
    #pragma unroll
    for (int j = 0; j < 8; ++j)
      r.c[j] = (signed char)(((w >> (4 * j)) & 15) - zq);
    *(uint2*)(wt + (size_t)n * K_DIM + (size_t)k8 * 8) = r.u;
  }
}

// ---------------- stage 3: i8 GEMM 128x256, BK=128 (= one scale group) ----------------
// A = xq [M][K] i8, B = wt [N][K] i8. 8 waves (2M x 4N), per-wave 64x64.
// mfma_i32_16x16x64_i8; per tile: 2 ks-phases x 16 MFMA; 16 ds_read_b128/wave.
// Group-end (each tile): accf += s[g][col] * (float)acci; acci = 0  (VALU pipe,
// runs parallel to LDS/MFMA). Epilogue: out = sx[row] * accf + bias.
// LDS 96 KiB: 2 buf x (A 16KB + B 32KB). Rows are 128 B -> same XOR swizzle as
// bf16/BK64: 16B slot ^= (row&7) on stage source and on reads (involution).
// One barrier + vmcnt(0) per tile; buffer re-staged one full tile after its
// last (dataflow-drained) read -> race-free.

#define MFMA16(ks) do { \
  __builtin_amdgcn_s_setprio(1); \
  acci[0][0] = __builtin_amdgcn_mfma_i32_16x16x64_i8(af[0], bf[0], acci[0][0], 0, 0, 0); \
  acci[0][1] = __builtin_amdgcn_mfma_i32_16x16x64_i8(af[0], bf[1], acci[0][1], 0, 0, 0); \
  acci[0][2] = __builtin_amdgcn_mfma_i32_16x16x64_i8(af[0], bf[2], acci[0][2], 0, 0, 0); \
  acci[0][3] = __builtin_amdgcn_mfma_i32_16x16x64_i8(af[0], bf[3], acci[0][3], 0, 0, 0); \
  acci[1][0] = __builtin_amdgcn_mfma_i32_16x16x64_i8(af[1], bf[0], acci[1][0], 0, 0, 0); \
  acci[1][1] = __builtin_amdgcn_mfma_i32_16x16x64_i8(af[1], bf[1], acci[1][1], 0, 0, 0); \
  acci[1][2] = __builtin_amdgcn_mfma_i32_16x16x64_i8(af[1], bf[2], acci[1][2], 0, 0, 0); \
  acci[1][3] = __builtin_amdgcn_mfma_i32_16x16x64_i8(af[1], bf[3], acci[1][3], 0, 0, 0); \
  acci[2][0] = __builtin_amdgcn_mfma_i32_16x16x64_i8(af[2], bf[0], acci[2][0], 0, 0, 0); \
  acci[2][1] = __builtin_amdgcn_mfma_i32_16x16x64_i8(af[2], bf[1], acci[2][1], 0, 0, 0); \
  acci[2][2] = __builtin_amdgcn_mfma_i32_16x16x64_i8(af[2], bf[2], acci[2][2], 0, 0, 0); \
  acci[2][3] = __builtin_amdgcn_mfma_i32_16x16x64_i8(af[2], bf[3], acci[2][3], 0, 0, 0); \
  acci[3][0] = __builtin_amdgcn_mfma_i32_16x16x64_i8(af[3], bf[0], acci[3][0], 0, 0, 0); \
  acci[3][1] = __builtin_amdgcn_mfma_i32_16x16x64_i8(af[3], bf[1], acci[3][1], 0, 0, 0); \
  acci[3][2] = __builtin_amdgcn_mfma_i32_16x16x64_i8(af[3], bf[2], acci[3][2], 0, 0, 0); \
  acci[3][3] = __builtin_amdgcn_mfma_i32_16x16x64_i8(af[3], bf[3], acci[3][3], 0, 0, 0); \
  __builtin_amdgcn_s_setprio(0); \
} while (0)

// A(4) + B(4) fragments for ks-slice of buffer buf (byte ^= ks*64 walks slot)
#define LOADF(buf, ks) do { \
  const unsigned char* base_ = sh + (buf) * 49152; \
  af[0] = *(const i32x4*)(const void*)(base_ + (aoff0 ^ ((ks) << 6))); \
  af[1] = *(const i32x4*)(const void*)(base_ + (aoff1 ^ ((ks) << 6))); \
  af[2] = *(const i32x4*)(const void*)(base_ + (aoff2 ^ ((ks) << 6))); \
  af[3] = *(const i32x4*)(const void*)(base_ + (aoff3 ^ ((ks) << 6))); \
  bf[0] = *(const i32x4*)(const void*)(base_ + 16384 + (boff0 ^ ((ks) << 6))); \
  bf[1] = *(const i32x4*)(const void*)(base_ + 16384 + (boff1 ^ ((ks) << 6))); \
  bf[2] = *(const i32x4*)(const void*)(base_ + 16384 + (boff2 ^ ((ks) << 6))); \
  bf[3] = *(const i32x4*)(const void*)(base_ + 16384 + (boff3 ^ ((ks) << 6))); \
} while (0)

// stage tile kt into buffer buf: A 2 gloads/wave, B 4 gloads/wave
#define STAGE_ALL(buf, kt) do { \
  unsigned char* la_ = sh + (buf) * 49152 + w * 2048; \
  unsigned char* lb_ = sh + (buf) * 49152 + 16384 + w * 4096; \
  gload_lds16(pA + (kt) * 128, la_); \
  gload_lds16(pA + 8 * (size_t)K_DIM + (kt) * 128, la_ + 1024); \
  gload_lds16(pB + (kt) * 128, lb_); \
  gload_lds16(pB + 8 * (size_t)K_DIM + (kt) * 128, lb_ + 1024); \
  gload_lds16(pB + 16 * (size_t)K_DIM + (kt) * 128, lb_ + 2048); \
  gload_lds16(pB + 24 * (size_t)K_DIM + (kt) * 128, lb_ + 3072); \
} while (0)

#define WAIT_VM0 asm volatile("s_waitcnt vmcnt(0)" ::: "memory")
#define BAR() do { __builtin_amdgcn_s_barrier(); asm volatile("" ::: "memory"); } while (0)

__global__ __launch_bounds__(512, 2) void k_gemm8(const signed char* __restrict__ xq,
                                                  const signed char* __restrict__ wq,
                                                  const float* __restrict__ sc,
                                                  const float* __restrict__ sx,
                                                  const float* __restrict__ bias,
                                                  float* __restrict__ out) {
  __shared__ __align__(16) unsigned char sh[2 * 49152];  // 96 KiB

  const int nwg = gridDim.x;                 // 2752, % 8 == 0 -> bijective
  int bid = blockIdx.x;
  int swz = (bid & 7) * (nwg >> 3) + (bid >> 3);
  const int ntn = N_DIM / 256;               // 43
  int mt = swz / ntn;                        // 0..63 (M tiles of 128)
  int nt = swz % ntn;                        // 0..42 (N tiles of 256)

  const int tid = threadIdx.x;
  const int w = tid >> 6;        // wave 0..7
  const int lane = tid & 63;
  const int wm = w >> 2;         // 0..1: M half (64 rows each)
  const int wn = w & 3;          // 0..3: N quarter (64 cols each)
  const int fr = lane & 15;
  const int fq = lane >> 4;
  const int r7 = fr & 7;

  // staging source: per-lane pre-swizzled (involution slot^row), rows of 128 B
  const int srow = lane >> 3;                 // 0..7
  const int sslot = (lane & 7) ^ srow;        // 16B slot within the 128B row
  const size_t goff = (size_t)srow * K_DIM + (size_t)sslot * 16;
  const signed char* pA = xq + (size_t)(mt * 128 + w * 16) * K_DIM + goff;
  const signed char* pB = wq + (size_t)(nt * 256 + w * 32) * K_DIM + goff;

  // fragment byte offsets (ks0); ks1 = ^64 (slot = (ks*4+fq) ^ r7)
  const int swb = (fq ^ r7) << 4;
  const int aoff0 = (wm * 64 + 0 * 16 + fr) * 128 + swb;
  const int aoff1 = (wm * 64 + 1 * 16 + fr) * 128 + swb;
  const int aoff2 = (wm * 64 + 2 * 16 + fr) * 128 + swb;
  const int aoff3 = (wm * 64 + 3 * 16 + fr) * 128 + swb;
  const int boff0 = (wn * 64 + 0 * 16 + fr) * 128 + swb;
  const int boff1 = (wn * 64 + 1 * 16 + fr) * 128 + swb;
  const int boff2 = (wn * 64 + 2 * 16 + fr) * 128 + swb;
  const int boff3 = (wn * 64 + 3 * 16 + fr) * 128 + swb;

  const int c0 = nt * 256 + wn * 64 + fr;    // this lane's base output column

  i32x4 acci[4][4] = {};
  f32x4 accf[4][4] = {};
  i32x4 af[4], bf[4];

  // prologue: stage tile 0 into buf0
  STAGE_ALL(0, 0);
  WAIT_VM0;
  BAR();

  for (int t = 0; t < 32; ++t) {
    int buf = t & 1;
    if (t < 31) STAGE_ALL(buf ^ 1, t + 1);
    // group scales for this tile (group == tile since BK = 128 = GROUPSIZE)
    float sg0 = sc[(size_t)t * N_DIM + c0 + 0];
    float sg1 = sc[(size_t)t * N_DIM + c0 + 16];
    float sg2 = sc[(size_t)t * N_DIM + c0 + 32];
    float sg3 = sc[(size_t)t * N_DIM + c0 + 48];
    LOADF(buf, 0);
    MFMA16(0);
    LOADF(buf, 1);
    MFMA16(1);
    // group end: scale i32 partials into f32 accumulators, reset partials
    #pragma unroll
    for (int mi = 0; mi < 4; ++mi) {
      #pragma unroll
      for (int r = 0; r < 4; ++r) {
        accf[mi][0][r] += sg0 * (float)acci[mi][0][r];
        accf[mi][1][r] += sg1 * (float)acci[mi][1][r];
        accf[mi][2][r] += sg2 * (float)acci[mi][2][r];
        accf[mi][3][r] += sg3 * (float)acci[mi][3][r];
      }
      acci[mi][0] = (i32x4)(0); acci[mi][1] = (i32x4)(0);
      acci[mi][2] = (i32x4)(0); acci[mi][3] = (i32x4)(0);
    }
    WAIT_VM0;      // next tile's 6 gloads (issued at top) have landed
    BAR();
  }

  // epilogue: C/D layout col=lane&15, row=(lane>>4)*4+reg; out = sx[m]*accf + bias
  const int r0 = mt * 128 + wm * 64 + fq * 4;
  #pragma unroll
  for (int mi = 0; mi < 4; ++mi) {
    float sxr[4];
    #pragma unroll
    for (int r = 0; r < 4; ++r) sxr[r] = sx[r0 + mi * 16 + r];
    #pragma unroll
    for (int nj = 0; nj < 4; ++nj) {
      int col = c0 + nj * 16;
      float bv = bias[col];
      size_t base = (size_t)(r0 + mi * 16) * N_DIM + col;
      #pragma unroll
      for (int r = 0; r < 4; ++r)
        out[base + (size_t)r * N_DIM] = sxr[r] * accf[mi][nj][r] + bv;
    }
  }
}

// ---------------- fallback (ws too small): naive fp32 ----------------
__global__ void k_fallback(const float* __restrict__ x, const int* __restrict__ qw,
                           const int* __restrict__ qz, const float* __restrict__ sc,
                           const float* __restrict__ bias, float* __restrict__ out) {
  int n = blockIdx.x * blockDim.x + threadIdx.x;
  int m = blockIdx.y;
  const float* xr = x + (size_t)m * K_DIM;
  float acc = 0.f;
  for (int g = 0; g < 32; ++g) {
    float s = sc[g * N_DIM + n];
    int zq = (qz[g * (N_DIM / 8) + (n >> 3)] >> ((n & 7) * 4)) & 15;
    float zs = s * (float)zq;
    for (int k8 = g * 16; k8 < g * 16 + 16; ++k8) {
      int w = qw[(size_t)k8 * N_DIM + n];
      #pragma unroll
      for (int j = 0; j < 8; ++j) {
        float wf = s * (float)((w >> (4 * j)) & 15) - zs;
        acc += wf * xr[k8 * 8 + j];
      }
    }
  }
  out[(size_t)m * N_DIM + n] = acc + bias[n];
}

extern "C" void kernel_launch(void* const* d_in, const int* in_sizes, int n_in,
                              void* d_out, int out_size, void* d_ws, size_t ws_size,
                              hipStream_t stream) {
  const float* x  = (const float*)d_in[0];
  const int* qw   = (const int*)d_in[1];
  const int* qz   = (const int*)d_in[2];
  const float* sc = (const float*)d_in[3];
  const float* bias = (const float*)d_in[4];
  float* out = (float*)d_out;

  const size_t xq_bytes = (size_t)M_DIM * K_DIM;          // 33,554,432
  const size_t sx_bytes = (size_t)M_DIM * sizeof(float);  // 32,768
  const size_t wq_bytes = (size_t)N_DIM * K_DIM;          // 45,088,768
  const size_t need = xq_bytes + sx_bytes + wq_bytes;

  if (ws_size >= need) {
    signed char* xq = (signed char*)d_ws;
    float* sx = (float*)((char*)d_ws + xq_bytes);
    signed char* wq = (signed char*)((char*)d_ws + xq_bytes + sx_bytes);
    k_quant_x<<<dim3(M_DIM), dim3(256), 0, stream>>>(x, xq, sx);
    k_dequant_w8<<<dim3(N_DIM / 256, 64), dim3(256), 0, stream>>>(qw, qz, wq);
    k_gemm8<<<dim3((M_DIM / 128) * (N_DIM / 256)), dim3(512), 0, stream>>>(xq, wq, sc, sx, bias, out);
  } else {
    k_fallback<<<dim3(N_DIM / 256, M_DIM), dim3(256), 0, stream>>>(x, qw, qz, sc, bias, out);
  }
}

// Round 11
// 584.951 us; speedup vs baseline: 1.4554x; 1.0384x over previous
//
#include <hip/hip_runtime.h>
#include <hip/hip_bf16.h>
#include <stdint.h>

// QuantLinear GPTQ 4-bit: out[8192,11008] = x[8192,4096] . W[4096,11008] + bias
// i8 path: W' = (q - z) exact in i8; x quantized per-row to i8; per-group
// (128) scales applied on i32 partial accumulators; row scale at epilogue.
#define M_DIM 8192
#define K_DIM 4096
#define N_DIM 11008

typedef int i32x4 __attribute__((ext_vector_type(4)));
typedef float f32x4 __attribute__((ext_vector_type(4)));

typedef __attribute__((address_space(1))) const void global_cvoid;
typedef __attribute__((address_space(3))) void lds_void;

__device__ __forceinline__ void gload_lds16(const void* g, void* l) {
  // async global->LDS: each lane's 16B lands at lds_base + lane*16 (linear dest)
  __builtin_amdgcn_global_load_lds((global_cvoid*)g, (lds_void*)l, 16, 0, 0);
}

// ---------------- stage 1: per-row quantize x -> i8 + row scale ----------------
__global__ void k_quant_x(const float* __restrict__ x, signed char* __restrict__ xq,
                          float* __restrict__ sx) {
  int m = blockIdx.x;                       // 8192 rows
  int tx = threadIdx.x;                     // 256 threads, 16 floats each
  const float4* row = (const float4*)(x + (size_t)m * K_DIM);
  float4 v[4];
  float mx = 0.f;
  #pragma unroll
  for (int i = 0; i < 4; ++i) {
    v[i] = row[tx * 4 + i];
    mx = fmaxf(mx, fmaxf(fmaxf(fabsf(v[i].x), fabsf(v[i].y)),
                         fmaxf(fabsf(v[i].z), fabsf(v[i].w))));
  }
  #pragma unroll
  for (int off = 1; off < 64; off <<= 1)
    mx = fmaxf(mx, __shfl_xor(mx, off));
  __shared__ float wmx[4];
  if ((tx & 63) == 0) wmx[tx >> 6] = mx;
  __syncthreads();
  mx = fmaxf(fmaxf(wmx[0], wmx[1]), fmaxf(wmx[2], wmx[3]));
  mx = fmaxf(mx, 1e-20f);
  float scale = 127.0f / mx;
  if (tx == 0) sx[m] = mx / 127.0f;
  union { signed char c[16]; uint4 u; } p;
  #pragma unroll
  for (int i = 0; i < 4; ++i) {
    p.c[i * 4 + 0] = (signed char)(int)rintf(v[i].x * scale);
    p.c[i * 4 + 1] = (signed char)(int)rintf(v[i].y * scale);
    p.c[i * 4 + 2] = (signed char)(int)rintf(v[i].z * scale);
    p.c[i * 4 + 3] = (signed char)(int)rintf(v[i].w * scale);
  }
  ((uint4*)(xq + (size_t)m * K_DIM))[tx] = p.u;
}

// ---------------- stage 2: unpack W -> i8 W'^T [N][K], W' = q - z ----------------
__global__ void k_dequant_w8(const int* __restrict__ qw, const int* __restrict__ qz,
                             signed char* __restrict__ wt) {
  int n = blockIdx.x * blockDim.x + threadIdx.x;   // [0, 11008)
  int k8_0 = blockIdx.y * 8;                       // grid.y = 64
  int g = (k8_0 * 8) >> 7;                         // group, uniform per block
  int zq = (qz[g * (N_DIM / 8) + (n >> 3)] >> ((n & 7) * 4)) & 15;
  #pragma unroll
  for (int i = 0; i < 8; ++i) {
    int k8 = k8_0 + i;
    int w = qw[(size_t)k8 * N_DIM + n];
    union { signed char c[8]; uint2 u; } r;
    #pragma unroll
    for (int j = 0; j < 8; ++j)
      r.c[j] = (signed char)(((w >> (4 * j)) & 15) - zq);
    *(uint2*)(wt + (size_t)n * K_DIM + (size_t)k8 * 8) = r.u;
  }
}

// ---------------- stage 3: i8 GEMM 128x128, BK=128, 4 waves, 2 blocks/CU ----------------
// A = xq [M][K] i8, B = wt [N][K] i8. 4 waves (2M x 2N), per-wave 64x64.
// LDS 64 KiB (2 buf x (A 16KB + B 16KB)) -> TWO blocks co-resident per CU.
// Per-tile barrier+vmcnt locks only intra-block waves; the co-resident block
// is barrier-independent -> scheduler anti-phases the two blocks (one block's
// MFMA burst runs under the other's LDS-read burst) -- the m114 mechanism the
// single-block r8/r10 kernels lacked.
// Schedule/swizzle/numerics identical to the verified r10 kernel:
// stage(t+1) -> reads ks0 -> 16 MFMA -> reads ks1 -> 16 MFMA -> scale-fold ->
// vmcnt(0) -> barrier. Re-stage of a buffer is >=1 drained barrier after its
// last read (same audit as r10). Swizzle: 16B slot ^= (row&7) both sides.

#define MFMA16(ks) do { \
  __builtin_amdgcn_s_setprio(1); \
  acci[0][0] = __builtin_amdgcn_mfma_i32_16x16x64_i8(af[0], bf[0], acci[0][0], 0, 0, 0); \
  acci[0][1] = __builtin_amdgcn_mfma_i32_16x16x64_i8(af[0], bf[1], acci[0][1], 0, 0, 0); \
  acci[0][2] = __builtin_amdgcn_mfma_i32_16x16x64_i8(af[0], bf[2], acci[0][2], 0, 0, 0); \
  acci[0][3] = __builtin_amdgcn_mfma_i32_16x16x64_i8(af[0], bf[3], acci[0][3], 0, 0, 0); \
  acci[1][0] = __builtin_amdgcn_mfma_i32_16x16x64_i8(af[1], bf[0], acci[1][0], 0, 0, 0); \
  acci[1][1] = __builtin_amdgcn_mfma_i32_16x16x64_i8(af[1], bf[1], acci[1][1], 0, 0, 0); \
  acci[1][2] = __builtin_amdgcn_mfma_i32_16x16x64_i8(af[1], bf[2], acci[1][2], 0, 0, 0); \
  acci[1][3] = __builtin_amdgcn_mfma_i32_16x16x64_i8(af[1], bf[3], acci[1][3], 0, 0, 0); \
  acci[2][0] = __builtin_amdgcn_mfma_i32_16x16x64_i8(af[2], bf[0], acci[2][0], 0, 0, 0); \
  acci[2][1] = __builtin_amdgcn_mfma_i32_16x16x64_i8(af[2], bf[1], acci[2][1], 0, 0, 0); \
  acci[2][2] = __builtin_amdgcn_mfma_i32_16x16x64_i8(af[2], bf[2], acci[2][2], 0, 0, 0); \
  acci[2][3] = __builtin_amdgcn_mfma_i32_16x16x64_i8(af[2], bf[3], acci[2][3], 0, 0, 0); \
  acci[3][0] = __builtin_amdgcn_mfma_i32_16x16x64_i8(af[3], bf[0], acci[3][0], 0, 0, 0); \
  acci[3][1] = __builtin_amdgcn_mfma_i32_16x16x64_i8(af[3], bf[1], acci[3][1], 0, 0, 0); \
  acci[3][2] = __builtin_amdgcn_mfma_i32_16x16x64_i8(af[3], bf[2], acci[3][2], 0, 0, 0); \
  acci[3][3] = __builtin_amdgcn_mfma_i32_16x16x64_i8(af[3], bf[3], acci[3][3], 0, 0, 0); \
  __builtin_amdgcn_s_setprio(0); \
} while (0)

// A(4) + B(4) fragments for ks-slice of buffer buf (byte ^= ks*64 walks slot)
#define LOADF(buf, ks) do { \
  const unsigned char* base_ = sh + (buf) * 32768; \
  af[0] = *(const i32x4*)(const void*)(base_ + (aoff0 ^ ((ks) << 6))); \
  af[1] = *(const i32x4*)(const void*)(base_ + (aoff1 ^ ((ks) << 6))); \
  af[2] = *(const i32x4*)(const void*)(base_ + (aoff2 ^ ((ks) << 6))); \
  af[3] = *(const i32x4*)(const void*)(base_ + (aoff3 ^ ((ks) << 6))); \
  bf[0] = *(const i32x4*)(const void*)(base_ + 16384 + (boff0 ^ ((ks) << 6))); \
  bf[1] = *(const i32x4*)(const void*)(base_ + 16384 + (boff1 ^ ((ks) << 6))); \
  bf[2] = *(const i32x4*)(const void*)(base_ + 16384 + (boff2 ^ ((ks) << 6))); \
  bf[3] = *(const i32x4*)(const void*)(base_ + 16384 + (boff3 ^ ((ks) << 6))); \
} while (0)

// stage tile kt into buffer buf: 4 A-gloads + 4 B-gloads per wave
#define STAGE_ALL(buf, kt) do { \
  unsigned char* la_ = sh + (buf) * 32768 + w * 4096; \
  unsigned char* lb_ = la_ + 16384; \
  gload_lds16(pA + (kt) * 128, la_); \
  gload_lds16(pA + 8 * (size_t)K_DIM + (kt) * 128, la_ + 1024); \
  gload_lds16(pA + 16 * (size_t)K_DIM + (kt) * 128, la_ + 2048); \
  gload_lds16(pA + 24 * (size_t)K_DIM + (kt) * 128, la_ + 3072); \
  gload_lds16(pB + (kt) * 128, lb_); \
  gload_lds16(pB + 8 * (size_t)K_DIM + (kt) * 128, lb_ + 1024); \
  gload_lds16(pB + 16 * (size_t)K_DIM + (kt) * 128, lb_ + 2048); \
  gload_lds16(pB + 24 * (size_t)K_DIM + (kt) * 128, lb_ + 3072); \
} while (0)

#define WAIT_VM0 asm volatile("s_waitcnt vmcnt(0)" ::: "memory")
#define BAR() do { __builtin_amdgcn_s_barrier(); asm volatile("" ::: "memory"); } while (0)

__global__ __launch_bounds__(256, 2) void k_gemm8(const signed char* __restrict__ xq,
                                                  const signed char* __restrict__ wq,
                                                  const float* __restrict__ sc,
                                                  const float* __restrict__ sx,
                                                  const float* __restrict__ bias,
                                                  float* __restrict__ out) {
  __shared__ __align__(16) unsigned char sh[2 * 32768];  // 64 KiB -> 2 blocks/CU

  const int nwg = gridDim.x;                 // 5504, % 8 == 0 -> bijective
  int bid = blockIdx.x;
  int swz = (bid & 7) * (nwg >> 3) + (bid >> 3);
  const int ntn = N_DIM / 128;               // 86
  int mt = swz / ntn;                        // 0..63 (M tiles of 128)
  int nt = swz % ntn;                        // 0..85 (N tiles of 128)

  const int tid = threadIdx.x;
  const int w = tid >> 6;        // wave 0..3
  const int lane = tid & 63;
  const int wm = w >> 1;         // 0..1: M half (64 rows)
  const int wn = w & 1;          // 0..1: N half (64 cols)
  const int fr = lane & 15;
  const int fq = lane >> 4;
  const int r7 = fr & 7;

  // staging source: per-lane pre-swizzled (involution slot^row), rows of 128 B
  const int srow = lane >> 3;                 // 0..7
  const int sslot = (lane & 7) ^ srow;        // 16B slot within the 128B row
  const size_t goff = (size_t)srow * K_DIM + (size_t)sslot * 16;
  const signed char* pA = xq + (size_t)(mt * 128 + w * 32) * K_DIM + goff;
  const signed char* pB = wq + (size_t)(nt * 128 + w * 32) * K_DIM + goff;

  // fragment byte offsets (ks0); ks1 = ^64 (slot = (ks*4+fq) ^ r7)
  const int swb = (fq ^ r7) << 4;
  const int aoff0 = (wm * 64 + 0 * 16 + fr) * 128 + swb;
  const int aoff1 = (wm * 64 + 1 * 16 + fr) * 128 + swb;
  const int aoff2 = (wm * 64 + 2 * 16 + fr) * 128 + swb;
  const int aoff3 = (wm * 64 + 3 * 16 + fr) * 128 + swb;
  const int boff0 = (wn * 64 + 0 * 16 + fr) * 128 + swb;
  const int boff1 = (wn * 64 + 1 * 16 + fr) * 128 + swb;
  const int boff2 = (wn * 64 + 2 * 16 + fr) * 128 + swb;
  const int boff3 = (wn * 64 + 3 * 16 + fr) * 128 + swb;

  const int c0 = nt * 128 + wn * 64 + fr;    // this lane's base output column

  i32x4 acci[4][4] = {};
  f32x4 accf[4][4] = {};
  i32x4 af[4], bf[4];

  // prologue: stage tile 0 into buf0
  STAGE_ALL(0, 0);
  WAIT_VM0;
  BAR();

  for (int t = 0; t < 32; ++t) {
    int buf = t & 1;
    if (t < 31) STAGE_ALL(buf ^ 1, t + 1);
    // group scales for this tile (group == tile since BK = 128 = GROUPSIZE)
    float sg0 = sc[(size_t)t * N_DIM + c0 + 0];
    float sg1 = sc[(size_t)t * N_DIM + c0 + 16];
    float sg2 = sc[(size_t)t * N_DIM + c0 + 32];
    float sg3 = sc[(size_t)t * N_DIM + c0 + 48];
    LOADF(buf, 0);
    MFMA16(0);
    LOADF(buf, 1);
    MFMA16(1);
    // group end: scale i32 partials into f32 accumulators, reset partials
    #pragma unroll
    for (int mi = 0; mi < 4; ++mi) {
      #pragma unroll
      for (int r = 0; r < 4; ++r) {
        accf[mi][0][r] += sg0 * (float)acci[mi][0][r];
        accf[mi][1][r] += sg1 * (float)acci[mi][1][r];
        accf[mi][2][r] += sg2 * (float)acci[mi][2][r];
        accf[mi][3][r] += sg3 * (float)acci[mi][3][r];
      }
      acci[mi][0] = (i32x4)(0); acci[mi][1] = (i32x4)(0);
      acci[mi][2] = (i32x4)(0); acci[mi][3] = (i32x4)(0);
    }
    WAIT_VM0;      // next tile's 8 gloads (issued at top) have landed
    BAR();
  }

  // epilogue: C/D layout col=lane&15, row=(lane>>4)*4+reg; out = sx[m]*accf + bias
  const int r0 = mt * 128 + wm * 64 + fq * 4;
  #pragma unroll
  for (int mi = 0; mi < 4; ++mi) {
    float sxr[4];
    #pragma unroll
    for (int r = 0; r < 4; ++r) sxr[r] = sx[r0 + mi * 16 + r];
    #pragma unroll
    for (int nj = 0; nj < 4; ++nj) {
      int col = c0 + nj * 16;
      float bv = bias[col];
      size_t base = (size_t)(r0 + mi * 16) * N_DIM + col;
      #pragma unroll
      for (int r = 0; r < 4; ++r)
        out[base + (size_t)r * N_DIM] = sxr[r] * accf[mi][nj][r] + bv;
    }
  }
}

// ---------------- fallback (ws too small): naive fp32 ----------------
__global__ void k_fallback(const float* __restrict__ x, const int* __restrict__ qw,
                           const int* __restrict__ qz, const float* __restrict__ sc,
                           const float* __restrict__ bias, float* __restrict__ out) {
  int n = blockIdx.x * blockDim.x + threadIdx.x;
  int m = blockIdx.y;
  const float* xr = x + (size_t)m * K_DIM;
  float acc = 0.f;
  for (int g = 0; g < 32; ++g) {
    float s = sc[g * N_DIM + n];
    int zq = (qz[g * (N_DIM / 8) + (n >> 3)] >> ((n & 7) * 4)) & 15;
    float zs = s * (float)zq;
    for (int k8 = g * 16; k8 < g * 16 + 16; ++k8) {
      int w = qw[(size_t)k8 * N_DIM + n];
      #pragma unroll
      for (int j = 0; j < 8; ++j) {
        float wf = s * (float)((w >> (4 * j)) & 15) - zs;
        acc += wf * xr[k8 * 8 + j];
      }
    }
  }
  out[(size_t)m * N_DIM + n] = acc + bias[n];
}

extern "C" void kernel_launch(void* const* d_in, const int* in_sizes, int n_in,
                              void* d_out, int out_size, void* d_ws, size_t ws_size,
                              hipStream_t stream) {
  const float* x  = (const float*)d_in[0];
  const int* qw   = (const int*)d_in[1];
  const int* qz   = (const int*)d_in[2];
  const float* sc = (const float*)d_in[3];
  const float* bias = (const float*)d_in[4];
  float* out = (float*)d_out;

  const size_t xq_bytes = (size_t)M_DIM * K_DIM;          // 33,554,432
  const size_t sx_bytes = (size_t)M_DIM * sizeof(float);  // 32,768
  const size_t wq_bytes = (size_t)N_DIM * K_DIM;          // 45,088,768
  const size_t need = xq_bytes + sx_bytes + wq_bytes;

  if (ws_size >= need) {
    signed char* xq = (signed char*)d_ws;
    float* sx = (float*)((char*)d_ws + xq_bytes);
    signed char* wq = (signed char*)((char*)d_ws + xq_bytes + sx_bytes);
    k_quant_x<<<dim3(M_DIM), dim3(256), 0, stream>>>(x, xq, sx);
    k_dequant_w8<<<dim3(N_DIM / 256, 64), dim3(256), 0, stream>>>(qw, qz, wq);
    k_gemm8<<<dim3((M_DIM / 128) * (N_DIM / 128)), dim3(256), 0, stream>>>(xq, wq, sc, sx, bias, out);
  } else {
    k_fallback<<<dim3(N_DIM / 256, M_DIM), dim3(256), 0, stream>>>(x, qw, qz, sc, bias, out);
  }
}